// Round 4
// baseline (106.127 us; speedup 1.0000x reference)
//
#include <hip/hip_runtime.h>

typedef float v2f __attribute__((ext_vector_type(2)));

#define BLOCK 256
#define WAVES 4
#define PSELF 8                  // self points per lane
#define SELFS 512                // selves per block = 64 * PSELF
#define SPLIT 8                  // others-axis splits
#define CHUNK 512                // others staged per block
#define WCH   128                // others per wave = CHUNK/WAVES
#define NPTS  4096
#define BATCH 16
#define NMIN  ((size_t)2 * BATCH * NPTS)
#define WPAD  (SELFS + SELFS / 16)

// dist(s,o) = |s|^2 + 4*(|h|^2 + h.s)  where h = -o/2.
__global__ __launch_bounds__(BLOCK, 4) void chamfer_min_kernel(
    const float* __restrict__ p1, const float* __restrict__ p2,
    unsigned int* __restrict__ minbuf, int per_split)
{
    __shared__ float HX[CHUNK], HY[CHUNK], HZ[CHUNK];   // SoA, 6 KB
    __shared__ float wmin[WAVES][WPAD];                 // cross-wave combine

    const int tid  = threadIdx.x;
    const int lane = tid & 63;
    const int wv   = tid >> 6;
    const int s    = blockIdx.x & (SPLIT - 1);
    const int j    = blockIdx.x >> 3;        // self chunk 0..7 (512 pts each)
    const int b    = blockIdx.y;
    const int dir  = blockIdx.z;

    const float* selfp  = (dir == 0 ? p1 : p2) + (size_t)b * NPTS * 3;
    const float* otherp = (dir == 0 ? p2 : p1) + (size_t)b * NPTS * 3;

    // Stage h = -0.5*other as SoA: 128 threads x 4 pts, b128 writes stride-1.
    if (tid < CHUNK / 4) {
        const float4* src = (const float4*)(otherp + (size_t)s * CHUNK * 3);
        float4 a = src[tid * 3 + 0];
        float4 c = src[tid * 3 + 1];
        float4 e = src[tid * 3 + 2];
        // pts: (a.x,a.y,a.z)(a.w,c.x,c.y)(c.z,c.w,e.x)(e.y,e.z,e.w)
        ((float4*)HX)[tid] = make_float4(-0.5f * a.x, -0.5f * a.w,
                                         -0.5f * c.z, -0.5f * e.y);
        ((float4*)HY)[tid] = make_float4(-0.5f * a.y, -0.5f * c.x,
                                         -0.5f * c.w, -0.5f * e.z);
        ((float4*)HZ)[tid] = make_float4(-0.5f * a.z, -0.5f * c.y,
                                         -0.5f * e.x, -0.5f * e.w);
    }

    // Selves: 8 pts/lane, 24 contiguous floats = 6 float4. Explicit unpack,
    // NO pointer casts of private arrays (keeps everything in VGPRs).
    float xs[PSELF], ys[PSELF], zs[PSELF], ssq[PSELF];
    {
        const float4* src = (const float4*)(selfp + (size_t)j * SELFS * 3);
        float4 v0 = src[lane * 6 + 0], v1 = src[lane * 6 + 1];
        float4 v2 = src[lane * 6 + 2], v3 = src[lane * 6 + 3];
        float4 v4 = src[lane * 6 + 4], v5 = src[lane * 6 + 5];
        xs[0]=v0.x; ys[0]=v0.y; zs[0]=v0.z;
        xs[1]=v0.w; ys[1]=v1.x; zs[1]=v1.y;
        xs[2]=v1.z; ys[2]=v1.w; zs[2]=v2.x;
        xs[3]=v2.y; ys[3]=v2.z; zs[3]=v2.w;
        xs[4]=v3.x; ys[4]=v3.y; zs[4]=v3.z;
        xs[5]=v3.w; ys[5]=v4.x; zs[5]=v4.y;
        xs[6]=v4.z; ys[6]=v4.w; zs[6]=v5.x;
        xs[7]=v5.y; ys[7]=v5.z; zs[7]=v5.w;
#pragma unroll
        for (int p = 0; p < PSELF; ++p)
            ssq[p] = fmaf(xs[p], xs[p], fmaf(ys[p], ys[p], zs[p] * zs[p]));
    }
    // Pre-splatted packed selves (hoisted out of the hot loop).
    v2f sx[PSELF], sy[PSELF], sz[PSELF];
#pragma unroll
    for (int p = 0; p < PSELF; ++p) {
        sx[p] = (v2f){xs[p], xs[p]};
        sy[p] = (v2f){ys[p], ys[p]};
        sz[p] = (v2f){zs[p], zs[p]};
    }
    __syncthreads();

    float mlo[PSELF], mhi[PSELF];
#pragma unroll
    for (int p = 0; p < PSELF; ++p) { mlo[p] = 3.4e38f; mhi[p] = 3.4e38f; }

    // Each wave streams its 128-other quarter: 4 others per iter, packed x2.
    const float4* X4 = (const float4*)HX + wv * (WCH / 4);
    const float4* Y4 = (const float4*)HY + wv * (WCH / 4);
    const float4* Z4 = (const float4*)HZ + wv * (WCH / 4);
#pragma unroll 2
    for (int i = 0; i < WCH / 4; ++i) {
        float4 X = X4[i], Y = Y4[i], Z = Z4[i];
        v2f xa = {X.x, X.y}, xb = {X.z, X.w};
        v2f ya = {Y.x, Y.y}, yb = {Y.z, Y.w};
        v2f za = {Z.x, Z.y}, zb = {Z.z, Z.w};
        // |h|^2 for the 4 others, shared across all 8 selves.
        v2f wa = __builtin_elementwise_fma(xa, xa,
                 __builtin_elementwise_fma(ya, ya, za * za));
        v2f wb = __builtin_elementwise_fma(xb, xb,
                 __builtin_elementwise_fma(yb, yb, zb * zb));
#pragma unroll
        for (int p = 0; p < PSELF; ++p) {
            v2f t0 = __builtin_elementwise_fma(sx[p], xa,
                     __builtin_elementwise_fma(sy[p], ya,
                     __builtin_elementwise_fma(sz[p], za, wa)));
            v2f t1 = __builtin_elementwise_fma(sx[p], xb,
                     __builtin_elementwise_fma(sy[p], yb,
                     __builtin_elementwise_fma(sz[p], zb, wb)));
            mlo[p] = fminf(fminf(mlo[p], t0.x), t1.x);   // v_min3_f32
            mhi[p] = fminf(fminf(mhi[p], t0.y), t1.y);
        }
    }

    // d = |s|^2 + 4*min_inner, clamp >=0 (uint order == float order).
#pragma unroll
    for (int p = 0; p < PSELF; ++p) {
        float mn = fminf(mlo[p], mhi[p]);
        float d  = fmaxf(fmaf(4.0f, mn, ssq[p]), 0.0f);
        int slot = lane * PSELF + p;
        wmin[wv][slot + (slot >> 4)] = d;
    }
    __syncthreads();

    // Cross-wave combine: thread tid handles 2 self slots.
    const size_t base = ((size_t)dir * BATCH + b) * NPTS + (size_t)j * SELFS;
    if (per_split) {
        float* dstp = (float*)minbuf + (size_t)s * NMIN + base;
#pragma unroll
        for (int i = 0; i < 2; ++i) {
            int sl = tid * 2 + i;
            int ps = sl + (sl >> 4);
            float mn = fminf(fminf(wmin[0][ps], wmin[1][ps]),
                             fminf(wmin[2][ps], wmin[3][ps]));
            dstp[sl] = mn;
        }
    } else {
#pragma unroll
        for (int i = 0; i < 2; ++i) {
            int sl = tid * 2 + i;
            int ps = sl + (sl >> 4);
            float mn = fminf(fminf(wmin[0][ps], wmin[1][ps]),
                             fminf(wmin[2][ps], wmin[3][ps]));
            atomicMin(minbuf + base + sl, __float_as_uint(mn));
        }
    }
}

// per-split path: min over SPLIT planes, sum, atomicAdd (out pre-zeroed).
__global__ __launch_bounds__(256) void chamfer_reduce_split(
    const float* __restrict__ minbuf, float* __restrict__ out, float scale)
{
    int i = blockIdx.x * 256 + threadIdx.x;
    float mn = minbuf[i];
#pragma unroll
    for (int s = 1; s < SPLIT; ++s)
        mn = fminf(mn, minbuf[(size_t)s * NMIN + i]);
    float v = mn;
#pragma unroll
    for (int off = 32; off > 0; off >>= 1) v += __shfl_down(v, off, 64);
    __shared__ float ws4[4];
    int lane = threadIdx.x & 63, wv = threadIdx.x >> 6;
    if (lane == 0) ws4[wv] = v;
    __syncthreads();
    if (threadIdx.x == 0)
        atomicAdd(out, (ws4[0] + ws4[1] + ws4[2] + ws4[3]) * scale);
}

// atomic fallback: single block sums NMIN uint-bit floats, writes out.
__global__ __launch_bounds__(1024) void chamfer_reduce_atomicpath(
    const unsigned int* __restrict__ minbuf, float* __restrict__ out, float scale)
{
    float v = 0.f;
    for (size_t i = threadIdx.x; i < NMIN; i += 1024)
        v += __uint_as_float(minbuf[i]);
#pragma unroll
    for (int off = 32; off > 0; off >>= 1) v += __shfl_down(v, off, 64);
    __shared__ float ws16[16];
    int lane = threadIdx.x & 63, wv = threadIdx.x >> 6;
    if (lane == 0) ws16[wv] = v;
    __syncthreads();
    if (threadIdx.x == 0) {
        float t = 0.f;
#pragma unroll
        for (int k = 0; k < 16; ++k) t += ws16[k];
        out[0] = t * scale;
    }
}

extern "C" void kernel_launch(void* const* d_in, const int* in_sizes, int n_in,
                              void* d_out, int out_size, void* d_ws, size_t ws_size,
                              hipStream_t stream) {
    const float* p1 = (const float*)d_in[0];
    const float* p2 = (const float*)d_in[1];
    float* out = (float*)d_out;
    unsigned int* minbuf = (unsigned int*)d_ws;

    const size_t split_bytes = (size_t)SPLIT * NMIN * sizeof(unsigned int); // 4 MB
    const int per_split = (ws_size >= split_bytes) ? 1 : 0;

    dim3 grid(8 * SPLIT, BATCH, 2);   // 64 x 16 x 2 = 2048 blocks
    if (per_split) {
        hipMemsetAsync(out, 0, sizeof(float), stream);
        chamfer_min_kernel<<<grid, BLOCK, 0, stream>>>(p1, p2, minbuf, 1);
        chamfer_reduce_split<<<NMIN / 256, 256, 0, stream>>>(
            (const float*)minbuf, out, 1.0f / BATCH);
    } else {
        hipMemsetAsync(minbuf, 0xFF, NMIN * sizeof(unsigned int), stream);
        chamfer_min_kernel<<<grid, BLOCK, 0, stream>>>(p1, p2, minbuf, 0);
        chamfer_reduce_atomicpath<<<1, 1024, 0, stream>>>(minbuf, out, 1.0f / BATCH);
    }
}

// Round 6
// 98.830 us; speedup vs baseline: 1.0738x; 1.0738x over previous
//
#include <hip/hip_runtime.h>

typedef float v2f __attribute__((ext_vector_type(2)));

#define NPTS  4096
#define BATCH 16
#define BLOCK 1024
#define NWAVE 16
#define PSELF 8                  // self points per lane; 512 selves per block
#define SELFS 512
#define WOTH  256                // others per wave = 4096 / 16 waves
#define WMSTR 545                // wmin wave stride (545 % 32 == 1: conflict-free)

// VOP3P packed fp32: sources MUST be 64-bit VGPR pairs (single VGPR src is
// an invalid operand — R5 compile fail). Compiler won't auto-form these.
__device__ __forceinline__ v2f pk_fma(v2f a, v2f b, v2f c) {
    v2f d;
    asm("v_pk_fma_f32 %0, %1, %2, %3" : "=v"(d) : "v"(a), "v"(b), "v"(c));
    return d;
}
__device__ __forceinline__ v2f pk_mul(v2f a, v2f b) {
    v2f d;
    asm("v_pk_mul_f32 %0, %1, %2" : "=v"(d) : "v"(a), "v"(b));
    return d;
}

// dist(s,o) = |s|^2 + 4*(|h|^2 + h.s), h = -o/2. Track m = min(|h|^2 + h.s).
__global__ __launch_bounds__(BLOCK, 4) void chamfer_fused_kernel(
    const float* __restrict__ p1, const float* __restrict__ p2,
    float* __restrict__ out)
{
    __shared__ float smem[12288];          // 48 KB: HX|HY|HZ -> wmin|ssqs|psum
    float* HX = smem;
    float* HY = smem + 4096;
    float* HZ = smem + 8192;

    const int tid  = threadIdx.x;
    const int lane = tid & 63;
    const int wv   = tid >> 6;             // 0..15
    const int blk  = blockIdx.x;           // 0..255
    const int j    = blk & 7;              // self chunk (512 pts)
    const int b    = (blk >> 3) & 15;
    const int dir  = blk >> 7;

    const float* selfp  = (dir == 0 ? p1 : p2) + (size_t)b * NPTS * 3;
    const float* otherp = (dir == 0 ? p2 : p1) + (size_t)b * NPTS * 3;

    // Stage ALL 4096 others as h = -0.5*o, SoA. 1024 threads x 4 points.
    {
        const float4* src = (const float4*)otherp;
        float4 a = src[tid * 3 + 0];
        float4 c = src[tid * 3 + 1];
        float4 e = src[tid * 3 + 2];
        ((float4*)HX)[tid] = make_float4(-0.5f * a.x, -0.5f * a.w,
                                         -0.5f * c.z, -0.5f * e.y);
        ((float4*)HY)[tid] = make_float4(-0.5f * a.y, -0.5f * c.x,
                                         -0.5f * c.w, -0.5f * e.z);
        ((float4*)HZ)[tid] = make_float4(-0.5f * a.z, -0.5f * c.y,
                                         -0.5f * e.x, -0.5f * e.w);
    }

    // Selves: identical in all 16 waves (L1-served). 8 pts/lane = 6 float4.
    float ssq[PSELF];
    v2f sx[PSELF], sy[PSELF], sz[PSELF];   // splat pairs for VOP3P operands
    {
        const float4* src = (const float4*)(selfp + (size_t)j * SELFS * 3);
        float4 v0 = src[lane * 6 + 0], v1 = src[lane * 6 + 1];
        float4 v2 = src[lane * 6 + 2], v3 = src[lane * 6 + 3];
        float4 v4 = src[lane * 6 + 4], v5 = src[lane * 6 + 5];
        float xs[PSELF], ys[PSELF], zs[PSELF];
        xs[0]=v0.x; ys[0]=v0.y; zs[0]=v0.z;
        xs[1]=v0.w; ys[1]=v1.x; zs[1]=v1.y;
        xs[2]=v1.z; ys[2]=v1.w; zs[2]=v2.x;
        xs[3]=v2.y; ys[3]=v2.z; zs[3]=v2.w;
        xs[4]=v3.x; ys[4]=v3.y; zs[4]=v3.z;
        xs[5]=v3.w; ys[5]=v4.x; zs[5]=v4.y;
        xs[6]=v4.z; ys[6]=v4.w; zs[6]=v5.x;
        xs[7]=v5.y; ys[7]=v5.z; zs[7]=v5.w;
#pragma unroll
        for (int p = 0; p < PSELF; ++p) {
            ssq[p] = fmaf(xs[p], xs[p], fmaf(ys[p], ys[p], zs[p] * zs[p]));
            sx[p] = (v2f){xs[p], xs[p]};
            sy[p] = (v2f){ys[p], ys[p]};
            sz[p] = (v2f){zs[p], zs[p]};
        }
    }
    __syncthreads();

    float m[PSELF];
#pragma unroll
    for (int p = 0; p < PSELF; ++p) m[p] = 3.4e38f;

    // Each wave streams its private 256-other slice: 4 others / iter.
    const float4* X4 = (const float4*)HX + wv * (WOTH / 4);
    const float4* Y4 = (const float4*)HY + wv * (WOTH / 4);
    const float4* Z4 = (const float4*)HZ + wv * (WOTH / 4);
#pragma unroll 2
    for (int i = 0; i < WOTH / 4; ++i) {
        float4 X = X4[i], Y = Y4[i], Z = Z4[i];
        v2f xa = {X.x, X.y}, xb = {X.z, X.w};
        v2f ya = {Y.x, Y.y}, yb = {Y.z, Y.w};
        v2f za = {Z.x, Z.y}, zb = {Z.z, Z.w};
        v2f wa = pk_fma(za, za, pk_fma(ya, ya, pk_mul(xa, xa)));  // |h|^2
        v2f wb = pk_fma(zb, zb, pk_fma(yb, yb, pk_mul(xb, xb)));
#pragma unroll
        for (int p = 0; p < PSELF; ++p) {
            v2f t0 = pk_fma(sx[p], xa,
                     pk_fma(sy[p], ya,
                     pk_fma(sz[p], za, wa)));
            v2f t1 = pk_fma(sx[p], xb,
                     pk_fma(sy[p], yb,
                     pk_fma(sz[p], zb, wb)));
            m[p] = fminf(fminf(m[p], t0.x), t0.y);   // v_min3_f32
            m[p] = fminf(fminf(m[p], t1.x), t1.y);   // v_min3_f32
        }
    }
    __syncthreads();                       // SoA region dead; reuse for combine

    float* wmin = smem;                    // 16 waves x 545
    float* ssqs = smem + NWAVE * WMSTR;    // 8720 .. 9263
    float* psum = smem + NWAVE * WMSTR + 544;   // 9264 .. 9280
#pragma unroll
    for (int p = 0; p < PSELF; ++p) {
        int sl = lane * PSELF + p;
        wmin[wv * WMSTR + sl + (sl >> 4)] = m[p];
    }
    if (wv == 0) {
#pragma unroll
        for (int p = 0; p < PSELF; ++p) {
            int sl = lane * PSELF + p;
            ssqs[sl + (sl >> 4)] = ssq[p];
        }
    }
    __syncthreads();

    // Final per-self min across 16 waves + |s|^2, then block-wide sum.
    float d = 0.f;
    if (tid < SELFS) {
        int ps = tid + (tid >> 4);
        float mn = wmin[ps];
#pragma unroll
        for (int w = 1; w < NWAVE; ++w)
            mn = fminf(mn, wmin[w * WMSTR + ps]);
        d = fmaf(4.0f, mn, ssqs[ps]);
    }
#pragma unroll
    for (int off = 32; off > 0; off >>= 1) d += __shfl_down(d, off, 64);
    if (lane == 0) psum[wv] = d;
    __syncthreads();
    if (tid == 0) {
        float t = 0.f;
#pragma unroll
        for (int w = 0; w < NWAVE; ++w) t += psum[w];
        atomicAdd(out, t * (1.0f / BATCH));
    }
}

extern "C" void kernel_launch(void* const* d_in, const int* in_sizes, int n_in,
                              void* d_out, int out_size, void* d_ws, size_t ws_size,
                              hipStream_t stream) {
    const float* p1 = (const float*)d_in[0];
    const float* p2 = (const float*)d_in[1];
    float* out = (float*)d_out;
    (void)d_ws; (void)ws_size;

    hipMemsetAsync(out, 0, sizeof(float), stream);
    // 2 dir x 16 batch x 8 self-chunks = 256 blocks (one per CU).
    chamfer_fused_kernel<<<dim3(256), dim3(BLOCK), 0, stream>>>(p1, p2, out);
}